// Round 5
// baseline (605.264 us; speedup 1.0000x reference)
//
#include <hip/hip_runtime.h>
#include <hip/hip_bf16.h>

// RGCN 2-layer forward, gather formulation, zero accumulation atomics.
// count(deg + cnt2 per (rel,dst)) -> scan(offs) -> scatter (cursor atomics,
// count BAKED into sorted word: src|rel<<16|cnt<<21) ->
// l1: wave/4dsts, 8 edges x 8 lanes, register acc, shuffle reduce ->
// l2: wave/4dsts, phase A: 4 exclusive LDS slots s[ep][rel][h] (stride 17,
//     2-way banks = free), phase B: w2 in 64 regs/lane, butterfly, softmax.

constexpr int Nn = 50000;
constexpr int Hh = 16;
constexpr int Rr = 32;
constexpr int Cc = 8;
constexpr int Ee = 1600000;
constexpr int NBLK = (Nn + 255) / 256;   // 196

__device__ __forceinline__ float b2f(__hip_bfloat16 v) { return __bfloat162float(v); }

// --- 0. dtype sniff (bf16 vs fp32 delivery) -----------------------------------
__global__ void sniff_kernel(const unsigned short* __restrict__ w, int* __restrict__ flag) {
    if (blockIdx.x == 0 && threadIdx.x == 0) {
        int hits = 0;
        for (int i = 0; i < 64; ++i) {
            unsigned short u = w[2 * i];
            int e = (u >> 7) & 0xFF;
            if (e >= 100 && e <= 130) ++hits;
        }
        *flag = (hits >= 32) ? 1 : 0;   // 1 = bf16, 0 = fp32
    }
}

// --- 1. deg per dst + count per (rel,dst) -------------------------------------
__global__ void count_kernel(const int* __restrict__ dst, const int* __restrict__ et,
                             int* __restrict__ deg, int* __restrict__ cnt2) {
    int e = blockIdx.x * blockDim.x + threadIdx.x;
    if (e < Ee) {
        int d = dst[e];
        atomicAdd(&deg[d], 1);
        atomicAdd(&cnt2[et[e] * Nn + d], 1);
    }
}

// --- 2a. per-block exclusive scan + block sums --------------------------------
__global__ __launch_bounds__(256) void scan1_kernel(const int* __restrict__ deg,
                                                    int* __restrict__ offs,
                                                    int* __restrict__ bsum) {
    __shared__ int lsum[4];
    int tid = threadIdx.x, lane = tid & 63, w = tid >> 6;
    int i = blockIdx.x * 256 + tid;
    int v = (i < Nn) ? deg[i] : 0;
    int s = v;
#pragma unroll
    for (int o = 1; o < 64; o <<= 1) { int t = __shfl_up(s, o, 64); if (lane >= o) s += t; }
    if (lane == 63) lsum[w] = s;
    __syncthreads();
    int base = 0;
    for (int j = 0; j < w; ++j) base += lsum[j];
    int excl = base + s - v;
    if (i < Nn) offs[i] = excl;
    if (tid == 255) bsum[blockIdx.x] = excl + v;
}

// --- 2b. scan block sums (NBLK<=256); grand total -> offs[Nn] -----------------
__global__ __launch_bounds__(256) void scan2_kernel(const int* __restrict__ bsum,
                                                    int* __restrict__ carry,
                                                    int* __restrict__ offs) {
    __shared__ int lsum[4];
    int tid = threadIdx.x, lane = tid & 63, w = tid >> 6;
    int v = (tid < NBLK) ? bsum[tid] : 0;
    int s = v;
#pragma unroll
    for (int o = 1; o < 64; o <<= 1) { int t = __shfl_up(s, o, 64); if (lane >= o) s += t; }
    if (lane == 63) lsum[w] = s;
    __syncthreads();
    int base = 0;
    for (int j = 0; j < w; ++j) base += lsum[j];
    int excl = base + s - v;
    if (tid < NBLK) carry[tid] = excl;
    if (tid == 255) offs[Nn] = excl;
}

// --- 2c. add carries ----------------------------------------------------------
__global__ void scan3_kernel(int* __restrict__ offs, const int* __restrict__ carry) {
    int i = blockIdx.x * 256 + threadIdx.x;
    if (i < Nn) offs[i] += carry[blockIdx.x];
}

// --- 3. scatter into dst-sorted order; pack src | rel<<16 | cnt<<21 -----------
__global__ void scatter_kernel(const int* __restrict__ src, const int* __restrict__ dst,
                               const int* __restrict__ et, const int* __restrict__ offs,
                               const int* __restrict__ cnt2, int* __restrict__ cursor,
                               unsigned int* __restrict__ sorted) {
    int e = blockIdx.x * blockDim.x + threadIdx.x;
    if (e < Ee) {
        int d = dst[e], r = et[e];
        int c = cnt2[r * Nn + d];
        c = c < 2047 ? c : 2047;
        int pos = offs[d] + atomicAdd(&cursor[d], 1);
        sorted[pos] = (unsigned)src[e] | ((unsigned)r << 16) | ((unsigned)c << 21);
    }
}

// --- 4. layer 1: wave per 4 dsts, 8 edges x 8 lanes, register acc -------------
__global__ __launch_bounds__(256) void l1_kernel(const unsigned int* __restrict__ sorted,
                                                 const int* __restrict__ offs,
                                                 const void* __restrict__ w1,
                                                 const void* __restrict__ root1,
                                                 const void* __restrict__ b1,
                                                 const int* __restrict__ flag,
                                                 float* __restrict__ x) {
    int tid = threadIdx.x, w = tid >> 6, lane = tid & 63;
    int ep = lane >> 3, hp = lane & 7;
    int isbf = *flag;
    int dbase = blockIdx.x * 16 + w * 4;          // 3125*16 == Nn
    for (int dd = 0; dd < 4; ++dd) {
        int d = dbase + dd;
        int off = offs[d], deg = offs[d + 1] - off;
        float a0 = 0.0f, a1 = 0.0f;
#pragma unroll 2
        for (int i = ep; i < deg; i += 8) {
            unsigned p = sorted[off + i];
            int cnt = p >> 21, rel = (p >> 16) & 31, s = p & 0xFFFF;
            float inv = __builtin_amdgcn_rcpf((float)cnt);
            size_t rowoff = ((size_t)rel * Nn + s) * 8 + hp;   // 8B units
            float f0, f1;
            if (isbf) {
                __hip_bfloat162 v = ((const __hip_bfloat162*)w1)[rowoff];
                f0 = __low2float(v); f1 = __high2float(v);
            } else {
                float2 v = ((const float2*)w1)[rowoff];
                f0 = v.x; f1 = v.y;
            }
            a0 += inv * f0; a1 += inv * f1;
        }
#pragma unroll
        for (int o = 8; o < 64; o <<= 1) {
            a0 += __shfl_xor(a0, o, 64);
            a1 += __shfl_xor(a1, o, 64);
        }
        if (ep == 0) {
            float r0, r1v, bb0, bb1;
            if (isbf) {
                r0  = b2f(((const __hip_bfloat16*)root1)[d * Hh + hp * 2]);
                r1v = b2f(((const __hip_bfloat16*)root1)[d * Hh + hp * 2 + 1]);
                bb0 = b2f(((const __hip_bfloat16*)b1)[hp * 2]);
                bb1 = b2f(((const __hip_bfloat16*)b1)[hp * 2 + 1]);
            } else {
                r0  = ((const float*)root1)[d * Hh + hp * 2];
                r1v = ((const float*)root1)[d * Hh + hp * 2 + 1];
                bb0 = ((const float*)b1)[hp * 2];
                bb1 = ((const float*)b1)[hp * 2 + 1];
            }
            float v0 = a0 + r0 + bb0, v1 = a1 + r1v + bb1;
            float2 st = make_float2(v0 > 0.f ? v0 : 0.f, v1 > 0.f ? v1 : 0.f);
            *(float2*)(x + (size_t)d * Hh + hp * 2) = st;
        }
    }
}

// --- 5. layer 2 + epilogue: wave per 4 dsts, exclusive LDS slots, w2 in regs --
__global__ __launch_bounds__(256) void l2_kernel(const unsigned int* __restrict__ sorted,
                                                 const int* __restrict__ offs,
                                                 const float* __restrict__ x,
                                                 const void* __restrict__ w2,
                                                 const void* __restrict__ root2,
                                                 const void* __restrict__ b2v,
                                                 const int* __restrict__ flag,
                                                 void* __restrict__ out) {
    __shared__ float smem[4 * 2176];   // 4 waves x 4 slots x (32 rel x 17)
    __shared__ float rsh[128];         // root2 fp32 [16][8]
    __shared__ float b2sh[8];
    int tid = threadIdx.x, w = tid >> 6, lane = tid & 63;
    int isbf = *flag;
    if (tid < 128) rsh[tid] = isbf ? b2f(((const __hip_bfloat16*)root2)[tid])
                                   : ((const float*)root2)[tid];
    if (tid < 8)   b2sh[tid] = isbf ? b2f(((const __hip_bfloat16*)b2v)[tid])
                                    : ((const float*)b2v)[tid];
    float* ms = smem + w * 2176;
    for (int k = lane; k < 2176; k += 64) ms[k] = 0.0f;
    // per-lane w2 fragment: lane=(r,half) holds w2[r][half*8 .. +8)[0..8) in regs
    int r = lane >> 1, half = lane & 1, hbase = half * 8;
    float w2f[64];
    {
        int base = r * 128 + half * 64;
        if (isbf) {
            const __hip_bfloat16* W = (const __hip_bfloat16*)w2 + base;
#pragma unroll
            for (int k = 0; k < 64; ++k) w2f[k] = b2f(W[k]);
        } else {
            const float* W = (const float*)w2 + base;
#pragma unroll
            for (int k = 0; k < 64; ++k) w2f[k] = W[k];
        }
    }
    __syncthreads();
    int ep = lane >> 4, h = lane & 15;
    int dbase = blockIdx.x * 16 + w * 4;
    for (int dd = 0; dd < 4; ++dd) {
        int d = dbase + dd;
        int off = offs[d], deg = offs[d + 1] - off;
        // phase A: s[ep][rel][h] += inv * x[src][h]; exclusive ownership, no atomics
        for (int i0 = 0; i0 < deg; i0 += 4) {
            int i = i0 + ep;
            if (i < deg) {
                unsigned p = sorted[off + i];
                int cnt = p >> 21, rel = (p >> 16) & 31, s = p & 0xFFFF;
                float inv = __builtin_amdgcn_rcpf((float)cnt);
                float xv = x[(size_t)s * Hh + h];
                ms[ep * 544 + rel * 17 + h] += inv * xv;
            }
        }
        __syncthreads();
        // phase B: pl[c] = sum_r sum_h s[r][h] * w2[r][h][c]; zero-after-read
        float pl[8];
#pragma unroll
        for (int c = 0; c < 8; ++c) pl[c] = 0.0f;
#pragma unroll
        for (int hh = 0; hh < 8; ++hh) {
            int col = hbase + hh;
            float sv = 0.0f;
#pragma unroll
            for (int e2 = 0; e2 < 4; ++e2) {
                int idx = e2 * 544 + r * 17 + col;
                sv += ms[idx];
                ms[idx] = 0.0f;
            }
#pragma unroll
            for (int c = 0; c < 8; ++c) pl[c] += sv * w2f[hh * 8 + c];
        }
        if (r == 0) {   // self-loop: x[d] @ root2, split across the 2 half-lanes
#pragma unroll
            for (int hh = 0; hh < 8; ++hh) {
                float xv = x[(size_t)d * Hh + hbase + hh];
#pragma unroll
                for (int c = 0; c < 8; ++c) pl[c] += xv * rsh[(hbase + hh) * 8 + c];
            }
        }
#pragma unroll
        for (int o = 1; o < 64; o <<= 1) {
#pragma unroll
            for (int c = 0; c < 8; ++c) pl[c] += __shfl_xor(pl[c], o, 64);
        }
#pragma unroll
        for (int c = 0; c < 8; ++c) pl[c] += b2sh[c];
        float m = pl[0];
#pragma unroll
        for (int c = 1; c < 8; ++c) m = fmaxf(m, pl[c]);
        float ssum = 0.0f;
#pragma unroll
        for (int c = 0; c < 8; ++c) ssum += __expf(pl[c] - m);
        float lse = m + __logf(ssum);
        if (lane == 0) {
            if (isbf) {
                union { unsigned short us[8]; uint4 v4; } o;
#pragma unroll
                for (int c = 0; c < 8; ++c) {
                    __hip_bfloat16 b = __float2bfloat16(pl[c] - lse);
                    o.us[c] = *(unsigned short*)&b;
                }
                *(uint4*)((__hip_bfloat16*)out + (size_t)d * Cc) = o.v4;
            } else {
                float* op = (float*)out + (size_t)d * Cc;
                ((float4*)op)[0] = make_float4(pl[0]-lse, pl[1]-lse, pl[2]-lse, pl[3]-lse);
                ((float4*)op)[1] = make_float4(pl[4]-lse, pl[5]-lse, pl[6]-lse, pl[7]-lse);
            }
        }
        __syncthreads();
    }
}

extern "C" void kernel_launch(void* const* d_in, const int* in_sizes, int n_in,
                              void* d_out, int out_size, void* d_ws, size_t ws_size,
                              hipStream_t stream) {
    const int* edge_index = (const int*)d_in[0];     // [2, E]
    const int* src = edge_index;
    const int* dst = edge_index + Ee;
    const int* et  = (const int*)d_in[1];            // [E]
    const void* w1    = d_in[2];  // [R,N,H]
    const void* root1 = d_in[3];  // [N,H]
    const void* b1    = d_in[4];  // [H]
    const void* w2    = d_in[5];  // [R,H,C]
    const void* root2 = d_in[6];  // [H,C]
    const void* b2    = d_in[7];  // [C]

    // ws (4B words): deg[Nn] | cursor[Nn] | cnt2[R*Nn] (reused as x[Nn*Hh]) |
    //                offs[Nn+4] | bsum[256] | carry[256] | sorted[Ee] | flag
    int* deg    = (int*)d_ws;
    int* cursor = deg + Nn;
    int* cnt2   = cursor + Nn;
    int* offs   = cnt2 + (size_t)Rr * Nn;
    int* bsum   = offs + Nn + 4;
    int* carry  = bsum + 256;
    unsigned int* sorted = (unsigned int*)(carry + 256);
    int* flag   = (int*)(sorted + Ee);
    float* x    = (float*)cnt2;    // cnt2 dead after scatter; x overlays it

    // zero deg + cursor + cnt2 (contiguous)
    hipMemsetAsync(d_ws, 0, (size_t)(2 * Nn + Rr * Nn) * sizeof(int), stream);

    sniff_kernel<<<1, 64, 0, stream>>>((const unsigned short*)w1, flag);
    count_kernel<<<(Ee + 255) / 256, 256, 0, stream>>>(dst, et, deg, cnt2);
    scan1_kernel<<<NBLK, 256, 0, stream>>>(deg, offs, bsum);
    scan2_kernel<<<1, 256, 0, stream>>>(bsum, carry, offs);
    scan3_kernel<<<NBLK, 256, 0, stream>>>(offs, carry);
    scatter_kernel<<<(Ee + 255) / 256, 256, 0, stream>>>(src, dst, et, offs, cnt2, cursor, sorted);
    l1_kernel<<<Nn / 16, 256, 0, stream>>>(sorted, offs, w1, root1, b1, flag, x);
    l2_kernel<<<Nn / 16, 256, 0, stream>>>(sorted, offs, x, w2, root2, b2, flag, d_out);
}

// Round 6
// 370.866 us; speedup vs baseline: 1.6320x; 1.6320x over previous
//
#include <hip/hip_runtime.h>
#include <hip/hip_bf16.h>

// RGCN 2-layer forward. dst-major, rel-grouped counting sort with ONE atomic
// per edge: packed-halfword count atomicAdd returns rank-in-(rel,dst)-segment;
// per-dst degree + per-rel starts derive from the packed count row, so
// scatter is atomic-free. l1/l2 are pure gather (zero accumulation atomics,
// zero per-edge LDS writes). cnt baked into sorted word: src|rel<<16|cnt<<21.

constexpr int Nn = 50000;
constexpr int Hh = 16;
constexpr int Rr = 32;
constexpr int Cc = 8;
constexpr int Ee = 1600000;
constexpr int NBLK = (Nn + 255) / 256;   // 196

__device__ __forceinline__ float b2f(__hip_bfloat16 v) { return __bfloat162float(v); }

// --- 0. dtype sniff (bf16 vs fp32 delivery) -----------------------------------
__global__ void sniff_kernel(const unsigned short* __restrict__ w, int* __restrict__ flag) {
    if (blockIdx.x == 0 && threadIdx.x == 0) {
        int hits = 0;
        for (int i = 0; i < 64; ++i) {
            unsigned short u = w[2 * i];
            int e = (u >> 7) & 0xFF;
            if (e >= 100 && e <= 130) ++hits;
        }
        *flag = (hits >= 32) ? 1 : 0;   // 1 = bf16, 0 = fp32
    }
}

// --- 1. packed count per (rel,dst); atomic return value = rank in segment -----
__global__ void count_kernel(const int* __restrict__ dst, const int* __restrict__ et,
                             unsigned* __restrict__ cnt2pk,
                             unsigned short* __restrict__ rank16) {
    int e = blockIdx.x * blockDim.x + threadIdx.x;
    if (e < Ee) {
        int d = dst[e], r = et[e];
        int word = d * 16 + (r >> 1);
        int sh = (r & 1) * 16;
        unsigned old = atomicAdd(&cnt2pk[word], 1u << sh);
        rank16[e] = (unsigned short)((old >> sh) & 0xFFFFu);
    }
}

// --- 2a. per-dst degree (sum of 32 packed counts) + block exclusive scan ------
__global__ __launch_bounds__(256) void scan1_kernel(const uint4* __restrict__ cnt2pk4,
                                                    int* __restrict__ offs,
                                                    int* __restrict__ bsum) {
    __shared__ int lsum[4];
    int tid = threadIdx.x, lane = tid & 63, w = tid >> 6;
    int d = blockIdx.x * 256 + tid;
    int v = 0;
    if (d < Nn) {
        const uint4* p = cnt2pk4 + (size_t)d * 4;
        uint4 a = p[0], b = p[1], c = p[2], q = p[3];
        unsigned s = a.x + a.y + a.z + a.w + b.x + b.y + b.z + b.w
                   + c.x + c.y + c.z + c.w + q.x + q.y + q.z + q.w;
        v = (int)((s & 0xFFFFu) + (s >> 16));   // halves can't overflow: deg<=65535
    }
    int s = v;
#pragma unroll
    for (int o = 1; o < 64; o <<= 1) { int t = __shfl_up(s, o, 64); if (lane >= o) s += t; }
    if (lane == 63) lsum[w] = s;
    __syncthreads();
    int base = 0;
    for (int j = 0; j < w; ++j) base += lsum[j];
    int excl = base + s - v;
    if (d < Nn) offs[d] = excl;
    if (tid == 255) bsum[blockIdx.x] = excl + v;
}

// --- 2b. scan block sums (NBLK<=256); grand total -> offs[Nn] -----------------
__global__ __launch_bounds__(256) void scan2_kernel(const int* __restrict__ bsum,
                                                    int* __restrict__ carry,
                                                    int* __restrict__ offs) {
    __shared__ int lsum[4];
    int tid = threadIdx.x, lane = tid & 63, w = tid >> 6;
    int v = (tid < NBLK) ? bsum[tid] : 0;
    int s = v;
#pragma unroll
    for (int o = 1; o < 64; o <<= 1) { int t = __shfl_up(s, o, 64); if (lane >= o) s += t; }
    if (lane == 63) lsum[w] = s;
    __syncthreads();
    int base = 0;
    for (int j = 0; j < w; ++j) base += lsum[j];
    int excl = base + s - v;
    if (tid < NBLK) carry[tid] = excl;
    if (tid == 255) offs[Nn] = excl;
}

// --- 2c. add carries ----------------------------------------------------------
__global__ void scan3_kernel(int* __restrict__ offs, const int* __restrict__ carry) {
    int i = blockIdx.x * 256 + threadIdx.x;
    if (i < Nn) offs[i] += carry[blockIdx.x];
}

// --- 3. atomic-free scatter; pos = offs[d] + relstart(d,r) + rank -------------
__global__ void scatter_kernel(const int* __restrict__ src, const int* __restrict__ dst,
                               const int* __restrict__ et, const int* __restrict__ offs,
                               const uint4* __restrict__ cnt2pk4,
                               const unsigned short* __restrict__ rank16,
                               unsigned* __restrict__ sorted) {
    int e = blockIdx.x * blockDim.x + threadIdx.x;
    if (e >= Ee) return;
    int d = dst[e], r = et[e];
    const uint4* p = cnt2pk4 + (size_t)d * 4;
    unsigned wd[16];
    uint4 a = p[0], b = p[1], c = p[2], q = p[3];
    wd[0]=a.x; wd[1]=a.y; wd[2]=a.z; wd[3]=a.w;
    wd[4]=b.x; wd[5]=b.y; wd[6]=b.z; wd[7]=b.w;
    wd[8]=c.x; wd[9]=c.y; wd[10]=c.z; wd[11]=c.w;
    wd[12]=q.x; wd[13]=q.y; wd[14]=q.z; wd[15]=q.w;
    int relstart = 0;
#pragma unroll
    for (int k = 0; k < 16; ++k) {
        int c0 = (int)(wd[k] & 0xFFFFu), c1 = (int)(wd[k] >> 16);
        if (2 * k     < r) relstart += c0;
        if (2 * k + 1 < r) relstart += c1;
    }
    unsigned u = wd[r >> 1];
    int cnt = (r & 1) ? (int)(u >> 16) : (int)(u & 0xFFFFu);
    cnt = cnt < 2047 ? cnt : 2047;
    int pos = offs[d] + relstart + (int)rank16[e];
    sorted[pos] = (unsigned)src[e] | ((unsigned)r << 16) | ((unsigned)cnt << 21);
}

// --- 4. layer 1: one wave per dst, 8 edges x 8 lanes (bf16x2/float2) ----------
__global__ __launch_bounds__(256) void l1_kernel(const unsigned* __restrict__ sorted,
                                                 const int* __restrict__ offs,
                                                 const void* __restrict__ w1,
                                                 const void* __restrict__ root1,
                                                 const void* __restrict__ b1,
                                                 const int* __restrict__ flag,
                                                 float* __restrict__ x) {
    int tid = threadIdx.x, w = tid >> 6, lane = tid & 63;
    int ep = lane >> 3, hp = lane & 7;
    int isbf = *flag;
    int d = blockIdx.x * 4 + w;                  // 12500*4 == Nn
    int off = offs[d], deg = offs[d + 1] - off;
    float a0 = 0.0f, a1 = 0.0f;
    if (isbf) {
#pragma unroll 2
        for (int i = ep; i < deg; i += 8) {
            unsigned p = sorted[off + i];
            int cnt = p >> 21, rel = (p >> 16) & 31, s = p & 0xFFFF;
            float inv = __builtin_amdgcn_rcpf((float)cnt);
            __hip_bfloat162 v = ((const __hip_bfloat162*)w1)[((size_t)rel * Nn + s) * 8 + hp];
            a0 += inv * __low2float(v); a1 += inv * __high2float(v);
        }
    } else {
#pragma unroll 2
        for (int i = ep; i < deg; i += 8) {
            unsigned p = sorted[off + i];
            int cnt = p >> 21, rel = (p >> 16) & 31, s = p & 0xFFFF;
            float inv = __builtin_amdgcn_rcpf((float)cnt);
            float2 v = ((const float2*)w1)[((size_t)rel * Nn + s) * 8 + hp];
            a0 += inv * v.x; a1 += inv * v.y;
        }
    }
#pragma unroll
    for (int o = 8; o < 64; o <<= 1) {
        a0 += __shfl_xor(a0, o, 64);
        a1 += __shfl_xor(a1, o, 64);
    }
    if (ep == 0) {
        float r0, r1v, bb0, bb1;
        if (isbf) {
            r0  = b2f(((const __hip_bfloat16*)root1)[d * Hh + hp * 2]);
            r1v = b2f(((const __hip_bfloat16*)root1)[d * Hh + hp * 2 + 1]);
            bb0 = b2f(((const __hip_bfloat16*)b1)[hp * 2]);
            bb1 = b2f(((const __hip_bfloat16*)b1)[hp * 2 + 1]);
        } else {
            r0  = ((const float*)root1)[d * Hh + hp * 2];
            r1v = ((const float*)root1)[d * Hh + hp * 2 + 1];
            bb0 = ((const float*)b1)[hp * 2];
            bb1 = ((const float*)b1)[hp * 2 + 1];
        }
        float v0 = a0 + r0 + bb0, v1 = a1 + r1v + bb1;
        *(float2*)(x + (size_t)d * Hh + hp * 2) =
            make_float2(v0 > 0.f ? v0 : 0.f, v1 > 0.f ? v1 : 0.f);
    }
}

// --- 5. layer 2 + epilogue: one wave per dst, 8 edges x 8 classes, reg dots ---
__global__ __launch_bounds__(256) void l2_kernel(const unsigned* __restrict__ sorted,
                                                 const int* __restrict__ offs,
                                                 const float* __restrict__ x,
                                                 const void* __restrict__ w2,
                                                 const void* __restrict__ root2,
                                                 const void* __restrict__ b2v,
                                                 const int* __restrict__ flag,
                                                 void* __restrict__ out) {
    __shared__ float w2s[32 * 132];   // [rel]*132 + c*16 + h  (pad 132: ~2-way banks)
    __shared__ float rsh[128];        // root2 [h*8+c]
    __shared__ float b2sh[8];
    int tid = threadIdx.x, w = tid >> 6, lane = tid & 63;
    int isbf = *flag;
    {
        int r = tid >> 3, cc = tid & 7;
        if (isbf) {
            const __hip_bfloat16* W = (const __hip_bfloat16*)w2 + r * 128 + cc;
#pragma unroll
            for (int h = 0; h < 16; ++h) w2s[r * 132 + cc * 16 + h] = b2f(W[h * 8]);
        } else {
            const float* W = (const float*)w2 + r * 128 + cc;
#pragma unroll
            for (int h = 0; h < 16; ++h) w2s[r * 132 + cc * 16 + h] = W[h * 8];
        }
    }
    if (tid < 128) rsh[tid] = isbf ? b2f(((const __hip_bfloat16*)root2)[tid])
                                   : ((const float*)root2)[tid];
    if (tid < 8)   b2sh[tid] = isbf ? b2f(((const __hip_bfloat16*)b2v)[tid])
                                    : ((const float*)b2v)[tid];
    __syncthreads();
    int ep = lane >> 3, c = lane & 7;
    int d = blockIdx.x * 4 + w;
    int off = offs[d], deg = offs[d + 1] - off;
    float acc = 0.0f;
    for (int i0 = 0; i0 < deg; i0 += 8) {
        int i = i0 + ep;
        if (i < deg) {
            unsigned p = sorted[off + i];
            int cnt = p >> 21, rel = (p >> 16) & 31, s = p & 0xFFFF;
            float inv = __builtin_amdgcn_rcpf((float)cnt);
            const float4* xr = (const float4*)(x + (size_t)s * Hh);
            float4 x0 = xr[0], x1 = xr[1], x2 = xr[2], x3 = xr[3];
            const float4* wv = (const float4*)(w2s + rel * 132 + c * 16);
            float4 w0 = wv[0], w1v = wv[1], w2v = wv[2], w3 = wv[3];
            float dot = x0.x*w0.x + x0.y*w0.y + x0.z*w0.z + x0.w*w0.w
                      + x1.x*w1v.x + x1.y*w1v.y + x1.z*w1v.z + x1.w*w1v.w
                      + x2.x*w2v.x + x2.y*w2v.y + x2.z*w2v.z + x2.w*w2v.w
                      + x3.x*w3.x + x3.y*w3.y + x3.z*w3.z + x3.w*w3.w;
            acc += inv * dot;
        }
    }
    acc += __shfl_xor(acc, 8, 64);
    acc += __shfl_xor(acc, 16, 64);
    acc += __shfl_xor(acc, 32, 64);
    if (ep == 0) {
        const float4* xr = (const float4*)(x + (size_t)d * Hh);
        float4 x0 = xr[0], x1 = xr[1], x2 = xr[2], x3 = xr[3];
        float xv[16] = {x0.x,x0.y,x0.z,x0.w, x1.x,x1.y,x1.z,x1.w,
                        x2.x,x2.y,x2.z,x2.w, x3.x,x3.y,x3.z,x3.w};
        float v = acc + b2sh[c];
#pragma unroll
        for (int h = 0; h < 16; ++h) v += xv[h] * rsh[h * 8 + c];
        float m = v;
#pragma unroll
        for (int o = 1; o < 8; o <<= 1) m = fmaxf(m, __shfl_xor(m, o, 8));
        float ssum = __expf(v - m);
#pragma unroll
        for (int o = 1; o < 8; o <<= 1) ssum += __shfl_xor(ssum, o, 8);
        float res = v - m - __logf(ssum);
        if (isbf) ((__hip_bfloat16*)out)[(size_t)d * Cc + c] = __float2bfloat16(res);
        else      ((float*)out)[(size_t)d * Cc + c] = res;
    }
}

extern "C" void kernel_launch(void* const* d_in, const int* in_sizes, int n_in,
                              void* d_out, int out_size, void* d_ws, size_t ws_size,
                              hipStream_t stream) {
    const int* edge_index = (const int*)d_in[0];     // [2, E]
    const int* src = edge_index;
    const int* dst = edge_index + Ee;
    const int* et  = (const int*)d_in[1];            // [E]
    const void* w1    = d_in[2];  // [R,N,H]
    const void* root1 = d_in[3];  // [N,H]
    const void* b1    = d_in[4];  // [H]
    const void* w2    = d_in[5];  // [R,H,C]
    const void* root2 = d_in[6];  // [H,C]
    const void* b2    = d_in[7];  // [C]

    // ws (4B words, ~13.0 MB total):
    // cnt2pk[800000] (x[800000] overlays after scatter) | rank16[800000 w] |
    // offs[Nn+4] | bsum[256] | carry[256] | sorted[Ee] | flag[1]
    unsigned* cnt2pk = (unsigned*)d_ws;
    unsigned short* rank16 = (unsigned short*)(cnt2pk + 800000);
    int* offs  = (int*)(rank16 + Ee);
    int* bsum  = offs + Nn + 4;
    int* carry = bsum + 256;
    unsigned* sorted = (unsigned*)(carry + 256);
    int* flag  = (int*)(sorted + Ee);
    float* x   = (float*)cnt2pk;     // overlay: cnt2pk dead after scatter

    hipMemsetAsync(cnt2pk, 0, 800000 * sizeof(unsigned), stream);

    sniff_kernel<<<1, 64, 0, stream>>>((const unsigned short*)w1, flag);
    count_kernel<<<(Ee + 255) / 256, 256, 0, stream>>>(dst, et, cnt2pk, rank16);
    scan1_kernel<<<NBLK, 256, 0, stream>>>((const uint4*)cnt2pk, offs, bsum);
    scan2_kernel<<<1, 256, 0, stream>>>(bsum, carry, offs);
    scan3_kernel<<<NBLK, 256, 0, stream>>>(offs, carry);
    scatter_kernel<<<(Ee + 255) / 256, 256, 0, stream>>>(src, dst, et, offs,
                                                         (const uint4*)cnt2pk, rank16, sorted);
    l1_kernel<<<Nn / 4, 256, 0, stream>>>(sorted, offs, w1, root1, b1, flag, x);
    l2_kernel<<<Nn / 4, 256, 0, stream>>>(sorted, offs, x, w2, root2, b2, flag, d_out);
}